// Round 3
// baseline (318.682 us; speedup 1.0000x reference)
//
#include <hip/hip_runtime.h>
#include <hip/hip_bf16.h>

typedef __bf16 bf16_t;
typedef __bf16 bf16x8 __attribute__((ext_vector_type(8)));
typedef float  f32x4  __attribute__((ext_vector_type(4)));

#define DDIM 1024
#define NTOK 1024
#define MATN (1024 * 1024)
#define BM 128
#define BN 128
#define BK 64
// ws: wt 18,874,368 + xb 2,097,152 + G 8,388,608 + meta 57,760  ~= 29.4 MiB

__device__ __forceinline__ void load16(const bf16_t* g, bf16_t* l) {
  // async global->LDS, 16B/lane. Global addr is PER-LANE; LDS dest is
  // wave-uniform base + lane*16 (m104/m108).
  __builtin_amdgcn_global_load_lds(
      (__attribute__((address_space(1))) void*)(g),
      (__attribute__((address_space(3))) void*)(l), 16, 0, 0);
}

// ---------------- init: zero expert counters ----------------
__global__ void init_k(int* counts) {
  if (threadIdx.x < 16) counts[threadIdx.x] = 0;
}

// ---------------- pad-slot init: list=0 (token 0), wrow=0 (zero weight) ----------------
__global__ void initslots_k(int* __restrict__ list, float* __restrict__ wrow) {
  const int i = blockIdx.x * 256 + threadIdx.x;  // grid 16*256 = 4096
  list[i] = 0; wrow[i] = 0.f;
}

// ---------------- x: fp32 -> bf16 ----------------
__global__ void convx_k(const float* __restrict__ x, bf16_t* __restrict__ xb) {
  const int i = (blockIdx.x * 256 + threadIdx.x) * 8;  // grid 512
  const f32x4 a = *(const f32x4*)(x + i);
  const f32x4 b = *(const f32x4*)(x + i + 4);
  bf16x8 v;
#pragma unroll
  for (int j = 0; j < 4; ++j) { v[j] = (bf16_t)a[j]; v[j + 4] = (bf16_t)b[j]; }
  *(bf16x8*)(xb + i) = v;
}

// ---------------- weight transpose+convert: fp32 src[k][n] -> bf16 dst[n][k] ----------------
__global__ void transpose_k(const float* __restrict__ src8, const float* __restrict__ srcS,
                            bf16_t* __restrict__ dst0) {
  const int e = blockIdx.z;
  const float* src = (e < 8) ? src8 + (size_t)e * MATN : srcS;
  bf16_t* dst = dst0 + (size_t)e * MATN;

  __shared__ bf16_t tile[64][65];  // +1 pad: <=2-way bank aliasing (free, m136)
  const int t = threadIdx.x;        // 256
  const int k0 = blockIdx.y * 64, n0 = blockIdx.x * 64;
  const int rr = t >> 3, cc = t & 7;
#pragma unroll
  for (int p = 0; p < 2; ++p) {
    const int r = rr + p * 32;
    const float* sp = src + (size_t)(k0 + r) * DDIM + n0 + cc * 8;
    const f32x4 a = *(const f32x4*)(sp);
    const f32x4 b = *(const f32x4*)(sp + 4);
#pragma unroll
    for (int j = 0; j < 4; ++j) {
      tile[r][cc * 8 + j]     = (bf16_t)a[j];
      tile[r][cc * 8 + 4 + j] = (bf16_t)b[j];
    }
  }
  __syncthreads();
#pragma unroll
  for (int p = 0; p < 2; ++p) {
    const int n = rr + p * 32;
    bf16x8 v;
#pragma unroll
    for (int j = 0; j < 8; ++j) v[j] = tile[cc * 8 + j][n];
    *(bf16x8*)(dst + (size_t)(n0 + n) * DDIM + k0 + cc * 8) = v;
  }
}

// ---------------- router: fp32 logits, softmax, top-2 (ties -> lowest idx) ----------------
__global__ void router_k(const float* __restrict__ x, const float* __restrict__ rw,
                         const float* __restrict__ bias, int* __restrict__ counts,
                         int* __restrict__ tsel, int* __restrict__ tpos,
                         float* __restrict__ tscore) {
  const int n = blockIdx.x;
  const int lane = threadIdx.x;  // 64
  float acc[8];
#pragma unroll
  for (int e = 0; e < 8; ++e) acc[e] = 0.f;
  for (int d = lane; d < DDIM; d += 64) {
    const float xv = x[n * DDIM + d];
    const f32x4 w0 = *(const f32x4*)(rw + d * 8);
    const f32x4 w1 = *(const f32x4*)(rw + d * 8 + 4);
#pragma unroll
    for (int e = 0; e < 4; ++e) { acc[e] += xv * w0[e]; acc[e + 4] += xv * w1[e]; }
  }
#pragma unroll
  for (int off = 32; off >= 1; off >>= 1)
#pragma unroll
    for (int e = 0; e < 8; ++e) acc[e] += __shfl_xor(acc[e], off, 64);

  if (lane == 0) {
    float mx = acc[0];
#pragma unroll
    for (int e = 1; e < 8; ++e) mx = fmaxf(mx, acc[e]);
    float p[8], s = 0.f;
#pragma unroll
    for (int e = 0; e < 8; ++e) { p[e] = __expf(acc[e] - mx); s += p[e]; }
    const float inv = 1.f / s;
    float sc[8], sb[8];
#pragma unroll
    for (int e = 0; e < 8; ++e) { sc[e] = p[e] * inv; sb[e] = sc[e] + bias[e]; }
    int i1 = 0;
#pragma unroll
    for (int e = 1; e < 8; ++e) if (sb[e] > sb[i1]) i1 = e;
    int i2 = (i1 == 0) ? 1 : 0;
#pragma unroll
    for (int e = 0; e < 8; ++e) if (e != i2 && e != i1 && sb[e] > sb[i2]) i2 = e;
    int pos = atomicAdd(&counts[i1], 1);
    tsel[n * 2 + 0] = i1; tpos[n * 2 + 0] = pos; tscore[n * 2 + 0] = sc[i1];
    pos = atomicAdd(&counts[i2], 1);
    tsel[n * 2 + 1] = i2; tpos[n * 2 + 1] = pos; tscore[n * 2 + 1] = sc[i2];
  }
}

// ---------------- scan: 128-padded per-expert slot bases + tile table ----------------
__global__ void scan_k(const int* __restrict__ counts, int* __restrict__ slot_base,
                       int* __restrict__ ntp, int* __restrict__ tile_e,
                       int* __restrict__ tile_m0) {
  if (threadIdx.x != 0) return;
  int pt = 0;
  for (int e = 0; e < 8; ++e) {
    slot_base[e] = pt * BM;
    const int nt = (counts[e] + BM - 1) / BM;
    for (int j = 0; j < nt; ++j) { tile_e[pt] = e; tile_m0[pt] = slot_base[e] + j * BM; ++pt; }
  }
  slot_base[8] = pt * BM;  // shared expert: 8 full tiles
  for (int j = 0; j < 8; ++j) { tile_e[pt] = 8; tile_m0[pt] = slot_base[8] + j * BM; ++pt; }
  ntp[0] = pt;  // <= 32
}

// ---------------- fill: scatter (token, score) into compacted slots ----------------
__global__ void fill_k(const int* __restrict__ tsel, const int* __restrict__ tpos,
                       const float* __restrict__ tscore, const int* __restrict__ slot_base,
                       int* __restrict__ list, float* __restrict__ wrow) {
  const int i = blockIdx.x * 256 + threadIdx.x;  // grid 12*256 = 3072
  if (i < 2048) {
    const int e = tsel[i];
    const int slot = slot_base[e] + tpos[i];
    list[slot] = i >> 1; wrow[slot] = tscore[i];
  } else {
    const int t = i - 2048;
    const int slot = slot_base[8] + t;
    list[slot] = t; wrow[slot] = 1.f;
  }
}

// ---------------- grouped GEMM (m97 structure), MODE: 0=U  1=V+SwiGLU  2=O ----------------
template <int MODE>
__global__ __launch_bounds__(256, 1)
void gemm_k(const bf16_t* __restrict__ xg, const bf16_t* __restrict__ wt,
            bf16_t* __restrict__ UG, float* __restrict__ oacc,
            const int* __restrict__ tile_e, const int* __restrict__ tile_m0,
            const int* __restrict__ ntp, const int* __restrict__ list,
            const float* __restrict__ wrow) {
  const int ti = blockIdx.y;
  if (ti >= ntp[0]) return;            // block-uniform -> no divergent barrier
  const int e = tile_e[ti];
  const int slot0 = tile_m0[ti];
  const int n0 = blockIdx.x * BN;

  __shared__ __align__(16) bf16_t sA[BM * BK];  // [m][k]
  __shared__ __align__(16) bf16_t sB[BN * BK];  // [n][k]

  const int tid = threadIdx.x;
  const int lane = tid & 63, wave = tid >> 6;
  const int wm = wave & 1, wn = wave >> 1;

  const bf16_t *aSrc[4], *bSrc[4];
#pragma unroll
  for (int i = 0; i < 4; ++i) {
    const int c = wave * 4 + i;              // chunk 0..15
    const int r = c * 8 + (lane >> 3);       // row 0..127
    const int slot = slot0 + r;              // < 4096 (padded tiles)
    if (MODE == 2) aSrc[i] = UG + (size_t)slot * DDIM + (lane & 7) * 8;
    else           aSrc[i] = xg + (size_t)list[slot] * DDIM + (lane & 7) * 8;
    bSrc[i] = wt + (size_t)e * MATN + (size_t)(n0 + r) * DDIM + (lane & 7) * 8;
  }

  const f32x4 z = {0.f, 0.f, 0.f, 0.f};
  f32x4 acc[4][4];
#pragma unroll
  for (int a = 0; a < 4; ++a)
#pragma unroll
    for (int b = 0; b < 4; ++b) acc[a][b] = z;

  for (int k0 = 0; k0 < DDIM; k0 += BK) {
#pragma unroll
    for (int i = 0; i < 4; ++i) {
      const int c = wave * 4 + i;
      load16(aSrc[i] + k0, sA + c * 512);
      load16(bSrc[i] + k0, sB + c * 512);
    }
    __syncthreads();
#pragma unroll
    for (int ks = 0; ks < 2; ++ks) {
      const int kk = ks * 32 + ((lane >> 4) * 8);
      bf16x8 af[4];
#pragma unroll
      for (int mf = 0; mf < 4; ++mf)
        af[mf] = *(const bf16x8*)(sA + (wm * 64 + mf * 16 + (lane & 15)) * BK + kk);
#pragma unroll
      for (int nf = 0; nf < 4; ++nf) {
        const bf16x8 fb = *(const bf16x8*)(sB + (wn * 64 + nf * 16 + (lane & 15)) * BK + kk);
#pragma unroll
        for (int mf = 0; mf < 4; ++mf)
          acc[mf][nf] = __builtin_amdgcn_mfma_f32_16x16x32_bf16(af[mf], fb, acc[mf][nf], 0, 0, 0);
      }
    }
    __syncthreads();
  }

  // C/D layout: col=lane&15, row=(lane>>4)*4+reg (m89/m91). Pads: wrow=0 -> contribute 0.
  const int colb = n0 + wn * 64 + (lane & 15);
#pragma unroll
  for (int mf = 0; mf < 4; ++mf) {
#pragma unroll
    for (int rg = 0; rg < 4; ++rg) {
      const int row = wm * 64 + mf * 16 + ((lane >> 4) * 4) + rg;
      const int slot = slot0 + row;
      if (MODE == 0) {
        bf16_t* gp = UG + (size_t)slot * DDIM + colb;
#pragma unroll
        for (int nf = 0; nf < 4; ++nf) gp[nf * 16] = (bf16_t)acc[mf][nf][rg];
      } else if (MODE == 1) {
        bf16_t* gp = UG + (size_t)slot * DDIM + colb;
#pragma unroll
        for (int nf = 0; nf < 4; ++nf) {
          const float u = (float)gp[nf * 16];                          // U = X W1^T
          const float g = (u / (1.f + __expf(-u))) * acc[mf][nf][rg];  // silu(U)*V
          gp[nf * 16] = (bf16_t)g;                                     // G in place
        }
      } else {
        const int tok = list[slot];
        const float w = wrow[slot];
        float* dst = oacc + (size_t)tok * DDIM + colb;
#pragma unroll
        for (int nf = 0; nf < 4; ++nf)
          atomicAdd(dst + nf * 16, w * acc[mf][nf][rg]);
      }
    }
  }
}

extern "C" void kernel_launch(void* const* d_in, const int* in_sizes, int n_in,
                              void* d_out, int out_size, void* d_ws, size_t ws_size,
                              hipStream_t stream) {
  (void)in_sizes; (void)n_in; (void)out_size; (void)ws_size;
  const float* x   = (const float*)d_in[0];
  const float* rw  = (const float*)d_in[1];
  const float* eb  = (const float*)d_in[2];
  const float* w1  = (const float*)d_in[3];
  const float* w2  = (const float*)d_in[4];
  const float* w3  = (const float*)d_in[5];
  const float* sw1 = (const float*)d_in[6];
  const float* sw2 = (const float*)d_in[7];
  const float* sw3 = (const float*)d_in[8];
  float* out = (float*)d_out;   // fp32 per reference; accumulate in place

  char* ws = (char*)d_ws;
  bf16_t* wt = (bf16_t*)(ws);                 // 9 * 2 MiB, reused for W1^T/W3^T/W2^T
  bf16_t* xb = (bf16_t*)(ws + 18874368);      // [1024][1024] bf16
  bf16_t* G  = (bf16_t*)(ws + 20971520);      // [4096][1024] bf16: U then G in place
  int*  meta = (int*)(ws + 29360128);
  int*   counts    = meta;                    // 16
  int*   slot_base = meta + 16;               // 16
  int*   ntp       = meta + 32;               // 8
  int*   tile_e    = meta + 40;               // 32
  int*   tile_m0   = meta + 72;               // 32
  int*   tsel      = meta + 104;              // 2048
  int*   tpos      = meta + 2152;             // 2048
  int*   list      = meta + 4200;             // 4096
  float* tscore    = (float*)(meta + 8296);   // 2048
  float* wrow      = (float*)(meta + 10344);  // 4096

  hipMemsetAsync(out, 0, (size_t)NTOK * DDIM * sizeof(float), stream);
  init_k<<<1, 64, 0, stream>>>(counts);
  initslots_k<<<16, 256, 0, stream>>>(list, wrow);
  convx_k<<<512, 256, 0, stream>>>(x, xb);
  router_k<<<NTOK, 64, 0, stream>>>(x, rw, eb, counts, tsel, tpos, tscore);
  scan_k<<<1, 64, 0, stream>>>(counts, slot_base, ntp, tile_e, tile_m0);
  fill_k<<<12, 256, 0, stream>>>(tsel, tpos, tscore, slot_base, list, wrow);

  // Stage 1: U = X W1^T
  transpose_k<<<dim3(16, 16, 9), 256, 0, stream>>>(w1, sw1, wt);
  gemm_k<0><<<dim3(8, 32), 256, 0, stream>>>(xb, wt, G, out, tile_e, tile_m0, ntp, list, wrow);
  // Stage 2: V = X W3^T, G = silu(U) * V (in place)
  transpose_k<<<dim3(16, 16, 9), 256, 0, stream>>>(w3, sw3, wt);
  gemm_k<1><<<dim3(8, 32), 256, 0, stream>>>(xb, wt, G, out, tile_e, tile_m0, ntp, list, wrow);
  // Stage 3: out[tok] += wrow * (G W2^T)
  transpose_k<<<dim3(16, 16, 9), 256, 0, stream>>>(w2, sw2, wt);
  gemm_k<2><<<dim3(8, 32), 256, 0, stream>>>(G, wt, G, out, tile_e, tile_m0, ntp, list, wrow);
}

// Round 4
// 282.690 us; speedup vs baseline: 1.1273x; 1.1273x over previous
//
#include <hip/hip_runtime.h>
#include <hip/hip_bf16.h>

typedef __bf16 bf16_t;
typedef __bf16 bf16x8 __attribute__((ext_vector_type(8)));
typedef float  f32x4  __attribute__((ext_vector_type(4)));

#define DDIM 1024
#define NTOK 1024
#define MATN (1024 * 1024)
#define TM 64      // tile rows (slots)
#define TN 64      // tile cols
#define BK 64
// ws: wt 18,874,368 + xb 2,097,152 + G 8,388,608 + meta 57,760  ~= 29.4 MiB (known good)

__device__ __forceinline__ void load16(const bf16_t* g, bf16_t* l) {
  // async global->LDS, 16B/lane. Global addr is PER-LANE; LDS dest is
  // wave-uniform base + lane*16 (m104/m108).
  __builtin_amdgcn_global_load_lds(
      (__attribute__((address_space(1))) void*)(g),
      (__attribute__((address_space(3))) void*)(l), 16, 0, 0);
}

// ---------------- prep: zero counters, init pad slots, convert x->bf16 ----------------
__global__ void prep_k(const float* __restrict__ x, bf16_t* __restrict__ xb,
                       int* __restrict__ counts, int* __restrict__ list,
                       float* __restrict__ wrow) {
  const int i = blockIdx.x * 256 + threadIdx.x;  // grid 512 -> 131072 threads
  const int j = i * 8;                            // 1M elements / 8
  const f32x4 a = *(const f32x4*)(x + j);
  const f32x4 b = *(const f32x4*)(x + j + 4);
  bf16x8 v;
#pragma unroll
  for (int t = 0; t < 4; ++t) { v[t] = (bf16_t)a[t]; v[t + 4] = (bf16_t)b[t]; }
  *(bf16x8*)(xb + j) = v;
  if (i < 16) counts[i] = 0;
  if (i < 4096) { list[i] = 0; wrow[i] = 0.f; }   // pad slots: token 0, weight 0
}

// ---------------- weight transpose+convert: fp32 src[k][n] -> bf16 dst[n][k] ----------------
__global__ void transpose_k(const float* __restrict__ src8, const float* __restrict__ srcS,
                            bf16_t* __restrict__ dst0) {
  const int e = blockIdx.z;
  const float* src = (e < 8) ? src8 + (size_t)e * MATN : srcS;
  bf16_t* dst = dst0 + (size_t)e * MATN;

  __shared__ bf16_t tile[64][65];  // +1 pad: <=2-way bank aliasing (free, m136)
  const int t = threadIdx.x;        // 256
  const int k0 = blockIdx.y * 64, n0 = blockIdx.x * 64;
  const int rr = t >> 3, cc = t & 7;
#pragma unroll
  for (int p = 0; p < 2; ++p) {
    const int r = rr + p * 32;
    const float* sp = src + (size_t)(k0 + r) * DDIM + n0 + cc * 8;
    const f32x4 a = *(const f32x4*)(sp);
    const f32x4 b = *(const f32x4*)(sp + 4);
#pragma unroll
    for (int j = 0; j < 4; ++j) {
      tile[r][cc * 8 + j]     = (bf16_t)a[j];
      tile[r][cc * 8 + 4 + j] = (bf16_t)b[j];
    }
  }
  __syncthreads();
#pragma unroll
  for (int p = 0; p < 2; ++p) {
    const int n = rr + p * 32;
    bf16x8 v;
#pragma unroll
    for (int j = 0; j < 8; ++j) v[j] = tile[cc * 8 + j][n];
    *(bf16x8*)(dst + (size_t)(n0 + n) * DDIM + k0 + cc * 8) = v;
  }
}

// ---------------- router: fp32 logits, softmax, top-2 (ties -> lowest idx) ----------------
__global__ void router_k(const float* __restrict__ x, const float* __restrict__ rw,
                         const float* __restrict__ bias, int* __restrict__ counts,
                         int* __restrict__ tsel, int* __restrict__ tpos,
                         float* __restrict__ tscore) {
  const int n = blockIdx.x;
  const int lane = threadIdx.x;  // 64
  float acc[8];
#pragma unroll
  for (int e = 0; e < 8; ++e) acc[e] = 0.f;
  for (int d = lane; d < DDIM; d += 64) {
    const float xv = x[n * DDIM + d];
    const f32x4 w0 = *(const f32x4*)(rw + d * 8);
    const f32x4 w1 = *(const f32x4*)(rw + d * 8 + 4);
#pragma unroll
    for (int e = 0; e < 4; ++e) { acc[e] += xv * w0[e]; acc[e + 4] += xv * w1[e]; }
  }
#pragma unroll
  for (int off = 32; off >= 1; off >>= 1)
#pragma unroll
    for (int e = 0; e < 8; ++e) acc[e] += __shfl_xor(acc[e], off, 64);

  if (lane == 0) {
    float mx = acc[0];
#pragma unroll
    for (int e = 1; e < 8; ++e) mx = fmaxf(mx, acc[e]);
    float p[8], s = 0.f;
#pragma unroll
    for (int e = 0; e < 8; ++e) { p[e] = __expf(acc[e] - mx); s += p[e]; }
    const float inv = 1.f / s;
    float sc[8], sb[8];
#pragma unroll
    for (int e = 0; e < 8; ++e) { sc[e] = p[e] * inv; sb[e] = sc[e] + bias[e]; }
    int i1 = 0;
#pragma unroll
    for (int e = 1; e < 8; ++e) if (sb[e] > sb[i1]) i1 = e;
    int i2 = (i1 == 0) ? 1 : 0;
#pragma unroll
    for (int e = 0; e < 8; ++e) if (e != i2 && e != i1 && sb[e] > sb[i2]) i2 = e;
    int pos = atomicAdd(&counts[i1], 1);
    tsel[n * 2 + 0] = i1; tpos[n * 2 + 0] = pos; tscore[n * 2 + 0] = sc[i1];
    pos = atomicAdd(&counts[i2], 1);
    tsel[n * 2 + 1] = i2; tpos[n * 2 + 1] = pos; tscore[n * 2 + 1] = sc[i2];
  }
}

// ---------------- scan: 64-padded per-expert slot bases + tile table ----------------
__global__ void scan_k(const int* __restrict__ counts, int* __restrict__ slot_base,
                       int* __restrict__ ntp, int* __restrict__ tile_e,
                       int* __restrict__ tile_m0) {
  if (threadIdx.x != 0) return;
  int pt = 0;
  for (int e = 0; e < 8; ++e) {
    slot_base[e] = pt * TM;
    const int nt = (counts[e] + TM - 1) / TM;
    for (int j = 0; j < nt; ++j) { tile_e[pt] = e; tile_m0[pt] = slot_base[e] + j * TM; ++pt; }
  }
  slot_base[8] = pt * TM;  // shared expert: 16 full tiles
  for (int j = 0; j < 16; ++j) { tile_e[pt] = 8; tile_m0[pt] = slot_base[8] + j * TM; ++pt; }
  ntp[0] = pt;  // <= 55
}

// ---------------- fill: scatter (token, score) into compacted slots ----------------
__global__ void fill_k(const int* __restrict__ tsel, const int* __restrict__ tpos,
                       const float* __restrict__ tscore, const int* __restrict__ slot_base,
                       int* __restrict__ list, float* __restrict__ wrow) {
  const int i = blockIdx.x * 256 + threadIdx.x;  // grid 12*256 = 3072
  if (i < 2048) {
    const int e = tsel[i];
    const int slot = slot_base[e] + tpos[i];
    list[slot] = i >> 1; wrow[slot] = tscore[i];
  } else {
    const int t = i - 2048;
    const int slot = slot_base[8] + t;
    list[slot] = t; wrow[slot] = 1.f;
  }
}

// ---------------- grouped GEMM, 64x64 tiles, MODE: 0=U  1=V+SwiGLU  2=O ----------------
// 64x64 tiles -> ~800 blocks -> 4+ blocks/CU co-resident (the m97 overlap mechanism).
// 128x128 gave only 192 blocks = 1 block/CU, 12.5% occupancy, fully exposed barriers.
template <int MODE>
__global__ __launch_bounds__(256, 4)
void gemm_k(const bf16_t* __restrict__ xg, const bf16_t* __restrict__ wt,
            bf16_t* __restrict__ UG, float* __restrict__ oacc,
            const int* __restrict__ tile_e, const int* __restrict__ tile_m0,
            const int* __restrict__ ntp, const int* __restrict__ list,
            const float* __restrict__ wrow) {
  const int ti = blockIdx.y;
  if (ti >= ntp[0]) return;            // block-uniform -> no divergent barrier
  const int e = tile_e[ti];
  const int slot0 = tile_m0[ti];
  const int n0 = blockIdx.x * TN;

  __shared__ __align__(16) bf16_t sA[TM * BK];  // 8 KB, [m][k]
  __shared__ __align__(16) bf16_t sB[TN * BK];  // 8 KB, [n][k]

  const int tid = threadIdx.x;
  const int lane = tid & 63, wave = tid >> 6;
  const int wm = wave & 1, wn = wave >> 1;

  const bf16_t *aSrc[2], *bSrc[2];
#pragma unroll
  for (int i = 0; i < 2; ++i) {
    const int c = wave * 2 + i;              // chunk 0..7
    const int r = c * 8 + (lane >> 3);       // row 0..63
    const int slot = slot0 + r;              // < 3520 (padded tiles)
    if (MODE == 2) aSrc[i] = xg + (size_t)slot * DDIM + (lane & 7) * 8;
    else           aSrc[i] = xg + (size_t)list[slot] * DDIM + (lane & 7) * 8;
    bSrc[i] = wt + (size_t)e * MATN + (size_t)(n0 + r) * DDIM + (lane & 7) * 8;
  }

  const f32x4 z = {0.f, 0.f, 0.f, 0.f};
  f32x4 acc[2][2];
#pragma unroll
  for (int a = 0; a < 2; ++a)
#pragma unroll
    for (int b = 0; b < 2; ++b) acc[a][b] = z;

  for (int k0 = 0; k0 < DDIM; k0 += BK) {
#pragma unroll
    for (int i = 0; i < 2; ++i) {
      const int c = wave * 2 + i;
      load16(aSrc[i] + k0, sA + c * 512);
      load16(bSrc[i] + k0, sB + c * 512);
    }
    __syncthreads();
#pragma unroll
    for (int ks = 0; ks < 2; ++ks) {
      const int kk = ks * 32 + ((lane >> 4) * 8);
      bf16x8 af[2];
#pragma unroll
      for (int mf = 0; mf < 2; ++mf)
        af[mf] = *(const bf16x8*)(sA + (wm * 32 + mf * 16 + (lane & 15)) * BK + kk);
#pragma unroll
      for (int nf = 0; nf < 2; ++nf) {
        const bf16x8 fb = *(const bf16x8*)(sB + (wn * 32 + nf * 16 + (lane & 15)) * BK + kk);
#pragma unroll
        for (int mf = 0; mf < 2; ++mf)
          acc[mf][nf] = __builtin_amdgcn_mfma_f32_16x16x32_bf16(af[mf], fb, acc[mf][nf], 0, 0, 0);
      }
    }
    __syncthreads();
  }

  // C/D layout: col=lane&15, row=(lane>>4)*4+reg (m89/m91). Pads: wrow=0 -> contribute 0.
  const int colb = n0 + wn * 32 + (lane & 15);
#pragma unroll
  for (int mf = 0; mf < 2; ++mf) {
#pragma unroll
    for (int rg = 0; rg < 4; ++rg) {
      const int row = wm * 32 + mf * 16 + ((lane >> 4) * 4) + rg;
      const int slot = slot0 + row;
      if (MODE == 0) {
        bf16_t* gp = UG + (size_t)slot * DDIM + colb;
#pragma unroll
        for (int nf = 0; nf < 2; ++nf) gp[nf * 16] = (bf16_t)acc[mf][nf][rg];
      } else if (MODE == 1) {
        bf16_t* gp = UG + (size_t)slot * DDIM + colb;
#pragma unroll
        for (int nf = 0; nf < 2; ++nf) {
          const float u = (float)gp[nf * 16];                          // U = X W1^T
          const float g = (u / (1.f + __expf(-u))) * acc[mf][nf][rg];  // silu(U)*V
          gp[nf * 16] = (bf16_t)g;                                     // G in place
        }
      } else {
        const int tok = list[slot];
        const float w = wrow[slot];
        float* dst = oacc + (size_t)tok * DDIM + colb;
#pragma unroll
        for (int nf = 0; nf < 2; ++nf)
          atomicAdd(dst + nf * 16, w * acc[mf][nf][rg]);
      }
    }
  }
}

extern "C" void kernel_launch(void* const* d_in, const int* in_sizes, int n_in,
                              void* d_out, int out_size, void* d_ws, size_t ws_size,
                              hipStream_t stream) {
  (void)in_sizes; (void)n_in; (void)out_size; (void)ws_size;
  const float* x   = (const float*)d_in[0];
  const float* rw  = (const float*)d_in[1];
  const float* eb  = (const float*)d_in[2];
  const float* w1  = (const float*)d_in[3];
  const float* w2  = (const float*)d_in[4];
  const float* w3  = (const float*)d_in[5];
  const float* sw1 = (const float*)d_in[6];
  const float* sw2 = (const float*)d_in[7];
  const float* sw3 = (const float*)d_in[8];
  float* out = (float*)d_out;   // fp32; accumulate in place

  char* ws = (char*)d_ws;
  bf16_t* wt = (bf16_t*)(ws);                 // 9 * 2 MiB, reused for W1^T/W3^T/W2^T
  bf16_t* xb = (bf16_t*)(ws + 18874368);      // [1024][1024] bf16
  bf16_t* G  = (bf16_t*)(ws + 20971520);      // [4096][1024] bf16: U then G in place
  int*  meta = (int*)(ws + 29360128);
  int*   counts    = meta;                    // 16
  int*   slot_base = meta + 16;               // 16
  int*   ntp       = meta + 32;               // 8
  int*   tile_e    = meta + 40;               // 64
  int*   tile_m0   = meta + 104;              // 64
  int*   tsel      = meta + 168;              // 2048
  int*   tpos      = meta + 2216;             // 2048
  int*   list      = meta + 4264;             // 4096
  float* tscore    = (float*)(meta + 8360);   // 2048
  float* wrow      = (float*)(meta + 10408);  // 4096

  hipMemsetAsync(out, 0, (size_t)NTOK * DDIM * sizeof(float), stream);
  prep_k<<<512, 256, 0, stream>>>(x, xb, counts, list, wrow);
  router_k<<<NTOK, 64, 0, stream>>>(x, rw, eb, counts, tsel, tpos, tscore);
  scan_k<<<1, 64, 0, stream>>>(counts, slot_base, ntp, tile_e, tile_m0);
  fill_k<<<12, 256, 0, stream>>>(tsel, tpos, tscore, slot_base, list, wrow);

  // Stage 1: U = X W1^T
  transpose_k<<<dim3(16, 16, 9), 256, 0, stream>>>(w1, sw1, wt);
  gemm_k<0><<<dim3(16, 56), 256, 0, stream>>>(xb, wt, G, out, tile_e, tile_m0, ntp, list, wrow);
  // Stage 2: V = X W3^T, G = silu(U) * V (in place)
  transpose_k<<<dim3(16, 16, 9), 256, 0, stream>>>(w3, sw3, wt);
  gemm_k<1><<<dim3(16, 56), 256, 0, stream>>>(xb, wt, G, out, tile_e, tile_m0, ntp, list, wrow);
  // Stage 3: out[tok] += wrow * (G W2^T)
  transpose_k<<<dim3(16, 16, 9), 256, 0, stream>>>(w2, sw2, wt);
  gemm_k<2><<<dim3(16, 56), 256, 0, stream>>>(G, wt, G, out, tile_e, tile_m0, ntp, list, wrow);
}